// Round 1
// baseline (275.706 us; speedup 1.0000x reference)
//
#include <hip/hip_runtime.h>
#include <stdint.h>

#define IN_F 4096
#define OUT_F 4096

typedef __attribute__((ext_vector_type(4))) float f32x4;
typedef __attribute__((ext_vector_type(8))) short short8;   // 8 bf16 (4 VGPRs)
typedef __attribute__((ext_vector_type(8))) __bf16 bfv8;
typedef __attribute__((ext_vector_type(4))) unsigned short u16x4;
typedef __attribute__((ext_vector_type(4))) int i32x4;

__device__ __forceinline__ unsigned short f2bf(float f) {
  __bf16 h = (__bf16)f;                       // compiler emits v_cvt (pairs fuse to cvt_pk)
  return __builtin_bit_cast(unsigned short, h);
}

// ---------------- workspace layout (bytes) ----------------
#define OFF_XB     ((size_t)0)            // bf16 x      [4096][4096]  33554432
#define OFF_PART   ((size_t)33554432)     // f32 partials[128][4096]    2097152
#define OFF_W      ((size_t)35651584)     // f32 w       [4096]           16384
#define OFF_BSUM   ((size_t)35667968)     // f32 bsum    [16]               256
#define OFF_INV    ((size_t)35668224)     // f32 inv     [1]                256
#define OFF_AW     ((size_t)35668480)     // bf16 A_w    [16][4096]      131072
#define OFF_BS     ((size_t)35799552)     // bf16 Bs     [4096][32]      262144
#define OFF_HPART  ((size_t)36061696)     // f32 hpart   [8][4096][16]  2097152
#define OFF_HB     ((size_t)38158848)     // bf16 hb     [4096][32]      262144
#define WS_NEED    ((size_t)38420992)

// K1: x -> bf16, plus per-column |x| partial sums (128 stripes x 32 rows)
__global__ __launch_bounds__(256) void k1_prep(const float* __restrict__ x,
                                               unsigned short* __restrict__ xb,
                                               float* __restrict__ part) {
  int t = threadIdx.x;
  int col4 = (blockIdx.x * 256 + t) * 4;
  int by = blockIdx.y;
  float a0 = 0.f, a1 = 0.f, a2 = 0.f, a3 = 0.f;
  for (int rr = 0; rr < 32; ++rr) {
    size_t off = (size_t)(by * 32 + rr) * IN_F + col4;
    f32x4 v = *(const f32x4*)(x + off);
    u16x4 o = { f2bf(v[0]), f2bf(v[1]), f2bf(v[2]), f2bf(v[3]) };
    *(u16x4*)(xb + off) = o;
    a0 += fabsf(v[0]); a1 += fabsf(v[1]); a2 += fabsf(v[2]); a3 += fabsf(v[3]);
  }
  f32x4 p = { a0, a1, a2, a3 };
  *(f32x4*)(part + (size_t)by * IN_F + col4) = p;
}

// K2: reduce stripes -> w[col] = mean|x| per column; per-block sums of w
__global__ __launch_bounds__(256) void k2_colred(const float* __restrict__ part,
                                                 float* __restrict__ w,
                                                 float* __restrict__ bsum) {
  int t = threadIdx.x;
  int col = blockIdx.x * 256 + t;
  float s = 0.f;
  for (int st = 0; st < 128; ++st) s += part[(size_t)st * IN_F + col];
  float wv = s * (1.0f / 4096.0f);
  w[col] = wv;
  __shared__ float red[256];
  red[t] = wv; __syncthreads();
  for (int k = 128; k > 0; k >>= 1) { if (t < k) red[t] += red[t + k]; __syncthreads(); }
  if (t == 0) bsum[blockIdx.x] = red[0];
}

// K3a: inv = 1/(mean(w)+1e-6)
__global__ void k3a_inv(const float* __restrict__ bsum, float* __restrict__ inv) {
  if (threadIdx.x == 0) {
    float s = 0.f;
    for (int i = 0; i < 16; ++i) s += bsum[i];
    float mean = s * (1.0f / 4096.0f);
    inv[0] = 1.0f / (mean + 1e-6f);
  }
}

// K3b: A_w[r][i] = (A0+A1)*w[i]*inv (bf16);  Bs[o][r] = 2*(B0+B1) padded to 32 (bf16)
__global__ __launch_bounds__(256) void k3b_fold(const float* __restrict__ lora_A,
                                                const float* __restrict__ lora_B,
                                                const float* __restrict__ w,
                                                const float* __restrict__ inv,
                                                unsigned short* __restrict__ A_w,
                                                unsigned short* __restrict__ Bs) {
  int b = blockIdx.x, t = threadIdx.x;
  float iv = inv[0];
  if (b < 256) {
    int idx = b * 256 + t;                 // [16][4096]
    int i = idx & (IN_F - 1);
    float v = (lora_A[idx] + lora_A[idx + 16 * IN_F]) * w[i] * iv;
    A_w[idx] = f2bf(v);
  } else {
    int idx = (b - 256) * 256 + t;         // [4096][32]
    int o = idx >> 5, r = idx & 31;
    float v = 0.f;
    if (r < 16) v = 2.0f * (lora_B[o * 16 + r] + lora_B[OUT_F * 16 + o * 16 + r]);
    Bs[idx] = f2bf(v);
  }
}

// K4: partial h: hpart[kc][m][r] = sum_{k in chunk} xb[m][k]*A_w[r][k]  (MFMA, K-split)
__global__ __launch_bounds__(256) void k4_h(const unsigned short* __restrict__ xb,
                                            const unsigned short* __restrict__ A_w,
                                            float* __restrict__ hpart) {
  int mb = blockIdx.x, kc = blockIdx.y;
  int t = threadIdx.x, wid = t >> 6, l = t & 63;
  int m0 = mb * 128 + wid * 32;
  int lr = l & 15, lg = l >> 4;
  f32x4 z = { 0.f, 0.f, 0.f, 0.f };
  f32x4 acc0 = z, acc1 = z;
  for (int it = 0; it < 16; ++it) {
    int k = kc * 512 + it * 32 + lg * 8;
    short8 b  = *(const short8*)(A_w + (size_t)lr * IN_F + k);
    short8 a0 = *(const short8*)(xb + (size_t)(m0 + lr) * IN_F + k);
    short8 a1 = *(const short8*)(xb + (size_t)(m0 + 16 + lr) * IN_F + k);
    acc0 = __builtin_amdgcn_mfma_f32_16x16x32_bf16(a0, b, acc0, 0, 0, 0);
    acc1 = __builtin_amdgcn_mfma_f32_16x16x32_bf16(a1, b, acc1, 0, 0, 0);
  }
  float* hp = hpart + (size_t)kc * IN_F * 16;
  #pragma unroll
  for (int r = 0; r < 4; ++r) {
    hp[(size_t)(m0 + lg * 4 + r) * 16 + lr]      = acc0[r];
    hp[(size_t)(m0 + 16 + lg * 4 + r) * 16 + lr] = acc1[r];
  }
}

// K5: reduce K-chunks -> hb[m][32] bf16 (cols 16..31 zero)
__global__ __launch_bounds__(256) void k5_hred(const float* __restrict__ hpart,
                                               unsigned short* __restrict__ hb) {
  int gid = blockIdx.x * 256 + threadIdx.x;   // 131072
  int m = gid >> 5, r = gid & 31;
  float v = 0.f;
  if (r < 16)
    for (int kc = 0; kc < 8; ++kc) v += hpart[(size_t)kc * 65536 + m * 16 + r];
  hb[gid] = f2bf(v);
}

// K6: main GEMM: out = xb * W + bias + hb*Bs^T   (fused int4 dequant in B staging)
__global__ __launch_bounds__(256) void k6_gemm(const unsigned short* __restrict__ xb,
                                               const int* __restrict__ qweight,
                                               const int* __restrict__ qzeros,
                                               const float* __restrict__ scales,
                                               const int* __restrict__ g_idx,
                                               const float* __restrict__ bias,
                                               const unsigned short* __restrict__ hb,
                                               const unsigned short* __restrict__ Bs,
                                               float* __restrict__ out) {
  __shared__ __align__(16) unsigned short As[128 * 64];   // [m][k] 16KB
  __shared__ __align__(16) unsigned short Bt[128 * 72];   // [n][k] padded stride 72 (18KB)
  int t = threadIdx.x, wid = t >> 6, l = t & 63;
  int bid = blockIdx.x;
  int mt = bid >> 5, nt = bid & 31;
  int m0 = mt * 128, n0 = nt * 128;
  int wm = wid >> 1, wn = wid & 1;
  int lr = l & 15, lg = l >> 4;
  int k8l = t >> 5;            // 0..7   packed-k row within tile
  int nl4 = (t & 31) * 4;      // 0..124 n within tile

  f32x4 z = { 0.f, 0.f, 0.f, 0.f };
  f32x4 acc[4][4];
  #pragma unroll
  for (int i = 0; i < 4; ++i)
    #pragma unroll
    for (int j = 0; j < 4; ++j) acc[i][j] = z;

  for (int kt = 0; kt < 64; ++kt) {
    int k0 = kt * 64;
    __syncthreads();
    // ---- A: async global->LDS (linear) ----
    #pragma unroll
    for (int it = 0; it < 4; ++it) {
      int idx = it * 256 + t;
      int row = idx >> 3, c = idx & 7;
      const unsigned short* gp = xb + (size_t)(m0 + row) * IN_F + k0 + c * 8;
      __builtin_amdgcn_global_load_lds((const __attribute__((address_space(1))) void*)gp,
                                       (__attribute__((address_space(3))) void*)(As + idx * 8),
                                       16, 0, 0);
    }
    // ---- B: fused int4 dequant into LDS [n][k] ----
    int grp = g_idx[k0];
    i32x4 qw = *(const i32x4*)(qweight + (size_t)((k0 >> 3) + k8l) * OUT_F + n0 + nl4);
    int zint = qzeros[grp * (OUT_F / 8) + ((n0 + nl4) >> 3)];
    f32x4 s4 = *(const f32x4*)(scales + (size_t)grp * OUT_F + n0 + nl4);
    #pragma unroll
    for (int j = 0; j < 4; ++j) {
      int q = qw[j];
      float sc = s4[j];
      float zv = (float)((zint >> (((nl4 + j) & 7) * 4)) & 0xF);
      float msz = -sc * zv;
      bfv8 pk;
      #pragma unroll
      for (int e = 0; e < 8; ++e) {
        float v = fmaf(sc, (float)((q >> (4 * e)) & 0xF), msz);
        pk[e] = (__bf16)v;
      }
      *(bfv8*)(Bt + (nl4 + j) * 72 + k8l * 8) = pk;
    }
    __syncthreads();
    // ---- MFMA: 2 k-steps of 32, 4x4 fragments per wave ----
    #pragma unroll
    for (int ks = 0; ks < 2; ++ks) {
      short8 af[4], bfr[4];
      #pragma unroll
      for (int i = 0; i < 4; ++i)
        af[i] = *(const short8*)(As + (wm * 64 + i * 16 + lr) * 64 + ks * 32 + lg * 8);
      #pragma unroll
      for (int j = 0; j < 4; ++j)
        bfr[j] = *(const short8*)(Bt + (wn * 64 + j * 16 + lr) * 72 + ks * 32 + lg * 8);
      #pragma unroll
      for (int i = 0; i < 4; ++i)
        #pragma unroll
        for (int j = 0; j < 4; ++j)
          acc[i][j] = __builtin_amdgcn_mfma_f32_16x16x32_bf16(af[i], bfr[j], acc[i][j], 0, 0, 0);
    }
  }

  // ---- epilogue: rank-16 LoRA update as one K=32 MFMA per fragment ----
  {
    short8 ah[4], bb[4];
    #pragma unroll
    for (int i = 0; i < 4; ++i)
      ah[i] = *(const short8*)(hb + (size_t)(m0 + wm * 64 + i * 16 + lr) * 32 + lg * 8);
    #pragma unroll
    for (int j = 0; j < 4; ++j)
      bb[j] = *(const short8*)(Bs + (size_t)(n0 + wn * 64 + j * 16 + lr) * 32 + lg * 8);
    #pragma unroll
    for (int i = 0; i < 4; ++i)
      #pragma unroll
      for (int j = 0; j < 4; ++j)
        acc[i][j] = __builtin_amdgcn_mfma_f32_16x16x32_bf16(ah[i], bb[j], acc[i][j], 0, 0, 0);
  }
  // ---- bias + store ----
  #pragma unroll
  for (int j = 0; j < 4; ++j) {
    float bv = bias[n0 + wn * 64 + j * 16 + lr];
    #pragma unroll
    for (int i = 0; i < 4; ++i) {
      int orow = m0 + wm * 64 + i * 16 + lg * 4;
      int ocol = n0 + wn * 64 + j * 16 + lr;
      #pragma unroll
      for (int r = 0; r < 4; ++r)
        out[(size_t)(orow + r) * OUT_F + ocol] = acc[i][j][r] + bv;
    }
  }
}

extern "C" void kernel_launch(void* const* d_in, const int* in_sizes, int n_in,
                              void* d_out, int out_size, void* d_ws, size_t ws_size,
                              hipStream_t stream) {
  const float* x       = (const float*)d_in[0];
  const float* scales  = (const float*)d_in[1];
  const float* bias    = (const float*)d_in[2];
  const float* lora_A  = (const float*)d_in[3];
  const float* lora_B  = (const float*)d_in[4];
  const int*   qweight = (const int*)d_in[5];
  const int*   qzeros  = (const int*)d_in[6];
  const int*   g_idx   = (const int*)d_in[7];
  float* out = (float*)d_out;

  if (ws_size < WS_NEED) return;   // leaves out zeroed -> clear diagnostic signature

  char* ws = (char*)d_ws;
  unsigned short* xb  = (unsigned short*)(ws + OFF_XB);
  float* part         = (float*)(ws + OFF_PART);
  float* w            = (float*)(ws + OFF_W);
  float* bsum         = (float*)(ws + OFF_BSUM);
  float* inv          = (float*)(ws + OFF_INV);
  unsigned short* A_w = (unsigned short*)(ws + OFF_AW);
  unsigned short* Bs  = (unsigned short*)(ws + OFF_BS);
  float* hpart        = (float*)(ws + OFF_HPART);
  unsigned short* hb  = (unsigned short*)(ws + OFF_HB);

  k1_prep<<<dim3(4, 128), 256, 0, stream>>>(x, xb, part);
  k2_colred<<<16, 256, 0, stream>>>(part, w, bsum);
  k3a_inv<<<1, 64, 0, stream>>>(bsum, inv);
  k3b_fold<<<768, 256, 0, stream>>>(lora_A, lora_B, w, inv, A_w, Bs);
  k4_h<<<dim3(32, 8), 256, 0, stream>>>(xb, A_w, hpart);
  k5_hred<<<512, 256, 0, stream>>>(hpart, hb);
  k6_gemm<<<1024, 256, 0, stream>>>(xb, qweight, qzeros, scales, g_idx, bias, hb, Bs, out);
}

// Round 2
// 206.513 us; speedup vs baseline: 1.3351x; 1.3351x over previous
//
#include <hip/hip_runtime.h>
#include <stdint.h>

#define IN_F 4096
#define OUT_F 4096

typedef __attribute__((ext_vector_type(4))) float f32x4;
typedef _Float16 f16x8 __attribute__((ext_vector_type(8)));
typedef _Float16 f16x2 __attribute__((ext_vector_type(2)));
typedef unsigned short u16x8 __attribute__((ext_vector_type(8)));

__device__ __forceinline__ unsigned short f2h(float f) {
  _Float16 h = (_Float16)f;
  return __builtin_bit_cast(unsigned short, h);
}

// k-permutation within each 8-group: position p holds original column sigma(p),
// sigma = [0,4,1,5,2,6,3,7]  (matches packed-f16 dequant output order)
#define SIGMA_TAB 0x73625140u

// ---------------- workspace layout (bytes) ----------------
#define OFF_XH     ((size_t)0)            // f16 x (col-permuted) [4096][4096]
#define OFF_PART   ((size_t)33554432)     // f32 partials[128][4096]
#define OFF_W      ((size_t)35651584)     // f32 w[4096]
#define OFF_BSUM   ((size_t)35667968)     // f32 bsum[16]
#define OFF_INV    ((size_t)35668224)     // f32 inv[1]
#define OFF_AW     ((size_t)35668480)     // f16 A_w[16][4096] (col-permuted)
#define OFF_BS     ((size_t)35799552)     // f16 Bs[4096][32]
#define OFF_HPART  ((size_t)36061696)     // f32 hpart[8][4096][16]
#define OFF_HB     ((size_t)38158848)     // f16 hb[4096][32]
#define WS_NEED    ((size_t)38420992)

// K1: x -> f16 (columns permuted within 8-groups) + per-column |x| partials
__global__ __launch_bounds__(256) void k1_prep(const float* __restrict__ x,
                                               unsigned short* __restrict__ xh,
                                               float* __restrict__ part) {
  int t = threadIdx.x;
  int c8 = (blockIdx.x * 256 + t) * 8;
  int by = blockIdx.y;
  float a[8];
  #pragma unroll
  for (int i = 0; i < 8; ++i) a[i] = 0.f;
  for (int rr = 0; rr < 32; ++rr) {
    size_t off = (size_t)(by * 32 + rr) * IN_F + c8;
    f32x4 v0 = *(const f32x4*)(x + off);
    f32x4 v1 = *(const f32x4*)(x + off + 4);
    u16x8 o;
    o[0] = f2h(v0[0]); o[1] = f2h(v1[0]); o[2] = f2h(v0[1]); o[3] = f2h(v1[1]);
    o[4] = f2h(v0[2]); o[5] = f2h(v1[2]); o[6] = f2h(v0[3]); o[7] = f2h(v1[3]);
    *(u16x8*)(xh + off) = o;
    a[0] += fabsf(v0[0]); a[1] += fabsf(v0[1]); a[2] += fabsf(v0[2]); a[3] += fabsf(v0[3]);
    a[4] += fabsf(v1[0]); a[5] += fabsf(v1[1]); a[6] += fabsf(v1[2]); a[7] += fabsf(v1[3]);
  }
  f32x4 p0 = { a[0], a[1], a[2], a[3] };
  f32x4 p1 = { a[4], a[5], a[6], a[7] };
  *(f32x4*)(part + (size_t)by * IN_F + c8) = p0;
  *(f32x4*)(part + (size_t)by * IN_F + c8 + 4) = p1;
}

// K2: reduce stripes -> w[col]; per-block sums of w
__global__ __launch_bounds__(256) void k2_colred(const float* __restrict__ part,
                                                 float* __restrict__ w,
                                                 float* __restrict__ bsum) {
  int t = threadIdx.x;
  int col = blockIdx.x * 256 + t;
  float s = 0.f;
  for (int st = 0; st < 128; ++st) s += part[(size_t)st * IN_F + col];
  float wv = s * (1.0f / 4096.0f);
  w[col] = wv;
  __shared__ float red[256];
  red[t] = wv; __syncthreads();
  for (int k = 128; k > 0; k >>= 1) { if (t < k) red[t] += red[t + k]; __syncthreads(); }
  if (t == 0) bsum[blockIdx.x] = red[0];
}

__global__ void k3a_inv(const float* __restrict__ bsum, float* __restrict__ inv) {
  if (threadIdx.x == 0) {
    float s = 0.f;
    for (int i = 0; i < 16; ++i) s += bsum[i];
    float mean = s * (1.0f / 4096.0f);
    inv[0] = 1.0f / (mean + 1e-6f);
  }
}

// K3b: A_w (col-permuted, f16);  Bs[o][r] = 2*(B0+B1) padded to 32 (f16)
__global__ __launch_bounds__(256) void k3b_fold(const float* __restrict__ lora_A,
                                                const float* __restrict__ lora_B,
                                                const float* __restrict__ w,
                                                const float* __restrict__ inv,
                                                unsigned short* __restrict__ A_w,
                                                unsigned short* __restrict__ Bs) {
  int b = blockIdx.x, t = threadIdx.x;
  float iv = inv[0];
  if (b < 256) {
    int idx = b * 256 + t;                 // [16][4096]
    int r = idx >> 12;
    int pos = idx & 4095;
    int p = pos & 7;
    int orig = (pos & ~7) + (int)((SIGMA_TAB >> (p * 4)) & 7);
    float v = (lora_A[(size_t)r * IN_F + orig] + lora_A[(size_t)(16 + r) * IN_F + orig]) * w[orig] * iv;
    A_w[idx] = f2h(v);
  } else {
    int idx = (b - 256) * 256 + t;         // [4096][32]
    int o = idx >> 5, r = idx & 31;
    float v = 0.f;
    if (r < 16) v = 2.0f * (lora_B[o * 16 + r] + lora_B[OUT_F * 16 + o * 16 + r]);
    Bs[idx] = f2h(v);
  }
}

// K4: hpart[kc][m][r] = sum_{k in chunk} xh[m][k]*A_w[r][k]  (f16 MFMA, K-split)
__global__ __launch_bounds__(256) void k4_h(const unsigned short* __restrict__ xh,
                                            const unsigned short* __restrict__ A_w,
                                            float* __restrict__ hpart) {
  int mb = blockIdx.x, kc = blockIdx.y;
  int t = threadIdx.x, wid = t >> 6, l = t & 63;
  int m0 = mb * 128 + wid * 32;
  int lr = l & 15, lg = l >> 4;
  f32x4 z = { 0.f, 0.f, 0.f, 0.f };
  f32x4 acc0 = z, acc1 = z;
  for (int it = 0; it < 16; ++it) {
    int k = kc * 512 + it * 32 + lg * 8;
    f16x8 b  = *(const f16x8*)(A_w + (size_t)lr * IN_F + k);
    f16x8 a0 = *(const f16x8*)(xh + (size_t)(m0 + lr) * IN_F + k);
    f16x8 a1 = *(const f16x8*)(xh + (size_t)(m0 + 16 + lr) * IN_F + k);
    acc0 = __builtin_amdgcn_mfma_f32_16x16x32_f16(a0, b, acc0, 0, 0, 0);
    acc1 = __builtin_amdgcn_mfma_f32_16x16x32_f16(a1, b, acc1, 0, 0, 0);
  }
  float* hp = hpart + (size_t)kc * IN_F * 16;
  #pragma unroll
  for (int r = 0; r < 4; ++r) {
    hp[(size_t)(m0 + lg * 4 + r) * 16 + lr]      = acc0[r];
    hp[(size_t)(m0 + 16 + lg * 4 + r) * 16 + lr] = acc1[r];
  }
}

// K5: reduce K-chunks -> hb[m][32] f16 (cols 16..31 zero)
__global__ __launch_bounds__(256) void k5_hred(const float* __restrict__ hpart,
                                               unsigned short* __restrict__ hb) {
  int gid = blockIdx.x * 256 + threadIdx.x;
  int m = gid >> 5, r = gid & 31;
  float v = 0.f;
  if (r < 16)
    for (int kc = 0; kc < 8; ++kc) v += hpart[(size_t)kc * 65536 + m * 16 + r];
  hb[gid] = f2h(v);
}

// packed f16 dequant: int32 (8 nibbles) -> f16x8 fragment, k-order [0,4,1,5,2,6,3,7]
__device__ __forceinline__ f16x8 deq8(unsigned int q, f16x2 s2, f16x2 zz2) {
  unsigned int u0 = ( q         & 0x000F000Fu) | 0x64006400u;
  unsigned int u1 = ((q >> 4)   & 0x000F000Fu) | 0x64006400u;
  unsigned int u2 = ((q >> 8)   & 0x000F000Fu) | 0x64006400u;
  unsigned int u3 = ((q >> 12)  & 0x000F000Fu) | 0x64006400u;
  f16x2 w0 = (__builtin_bit_cast(f16x2, u0) - zz2) * s2;
  f16x2 w1 = (__builtin_bit_cast(f16x2, u1) - zz2) * s2;
  f16x2 w2 = (__builtin_bit_cast(f16x2, u2) - zz2) * s2;
  f16x2 w3 = (__builtin_bit_cast(f16x2, u3) - zz2) * s2;
  struct { f16x2 a, b, c, d; } r { w0, w1, w2, w3 };
  return __builtin_bit_cast(f16x8, r);
}

// K6: out = xh * W + bias + hb*Bs^T.  128x128 tile, 4 waves each owning 128x32.
// A via swizzled global_load_lds; B dequantized straight into fragment registers.
__global__ __launch_bounds__(256) void k6_gemm(const unsigned short* __restrict__ xh,
                                               const int* __restrict__ qweight,
                                               const int* __restrict__ qzeros,
                                               const float* __restrict__ scales,
                                               const int* __restrict__ g_idx,
                                               const float* __restrict__ bias,
                                               const unsigned short* __restrict__ hb,
                                               const unsigned short* __restrict__ Bs,
                                               float* __restrict__ out) {
  __shared__ __align__(16) unsigned short As[128 * 64];   // 16KB, XOR-swizzled content
  int t = threadIdx.x, w = t >> 6, l = t & 63;
  int lr = l & 15, lg = l >> 4;
  int bid = blockIdx.x;
  int mt = bid >> 5, nt = bid & 31;
  int m0 = mt * 128, n0 = nt * 128;
  int ncol0 = n0 + w * 32 + lr;            // this lane's n for j=0 (j adds 16)

  f32x4 zz = { 0.f, 0.f, 0.f, 0.f };
  f32x4 acc[8][2];
  #pragma unroll
  for (int m = 0; m < 8; ++m) { acc[m][0] = zz; acc[m][1] = zz; }

  f16x2 s2[2], zp2[2];

  for (int kt = 0; kt < 64; ++kt) {
    int k0 = kt * 64;
    __syncthreads();
    // per-group constants (GROUP=128 -> every 2 K-tiles)
    if ((kt & 1) == 0) {
      int grp = g_idx[k0];
      #pragma unroll
      for (int j = 0; j < 2; ++j) {
        int n = ncol0 + j * 16;
        float s = scales[(size_t)grp * OUT_F + n];
        unsigned int zi = (unsigned int)qzeros[grp * (OUT_F / 8) + (n >> 3)];
        unsigned int z = (zi >> ((n & 7) * 4)) & 0xFu;
        unsigned int zzu = 0x64006400u + z * 0x00010001u;   // half2(1024+z)
        zp2[j] = __builtin_bit_cast(f16x2, zzu);
        _Float16 sh = (_Float16)s;
        unsigned int sb = (unsigned int)__builtin_bit_cast(unsigned short, sh);
        unsigned int ssu = (sb << 16) | sb;
        s2[j] = __builtin_bit_cast(f16x2, ssu);
      }
    }
    // B loads first (so the dequant's vmcnt wait leaves the A glds in flight)
    unsigned int qw[2][2];
    #pragma unroll
    for (int ks = 0; ks < 2; ++ks)
      #pragma unroll
      for (int j = 0; j < 2; ++j)
        qw[j][ks] = (unsigned int)qweight[(size_t)((k0 >> 3) + ks * 4 + lg) * OUT_F + ncol0 + j * 16];
    // A: async global->LDS, source chunk pre-swizzled (LDS dest linear)
    #pragma unroll
    for (int it = 0; it < 4; ++it) {
      int idx = it * 256 + t;
      int row = idx >> 3, c = idx & 7;
      int cp = c ^ (row & 7);
      const unsigned short* gp = xh + (size_t)(m0 + row) * IN_F + k0 + cp * 8;
      __builtin_amdgcn_global_load_lds((const __attribute__((address_space(1))) void*)gp,
                                       (__attribute__((address_space(3))) void*)(As + idx * 8),
                                       16, 0, 0);
    }
    // dequant into B fragments (register-only)
    f16x8 bf[2][2];
    #pragma unroll
    for (int ks = 0; ks < 2; ++ks)
      #pragma unroll
      for (int j = 0; j < 2; ++j)
        bf[j][ks] = deq8(qw[j][ks], s2[j], zp2[j]);
    __syncthreads();
    // MFMA: 16 swizzled A ds_reads, 32 MFMA
    #pragma unroll
    for (int ks = 0; ks < 2; ++ks) {
      f16x8 a[8];
      #pragma unroll
      for (int m = 0; m < 8; ++m) {
        int row = m * 16 + lr;
        int chunk = (ks * 4 + lg) ^ (lr & 7);
        a[m] = *(const f16x8*)(As + row * 64 + chunk * 8);
      }
      #pragma unroll
      for (int m = 0; m < 8; ++m) {
        acc[m][0] = __builtin_amdgcn_mfma_f32_16x16x32_f16(a[m], bf[0][ks], acc[m][0], 0, 0, 0);
        acc[m][1] = __builtin_amdgcn_mfma_f32_16x16x32_f16(a[m], bf[1][ks], acc[m][1], 0, 0, 0);
      }
    }
  }

  // epilogue: rank-16 LoRA as one K=32 f16 MFMA per fragment
  {
    f16x8 bb[2];
    #pragma unroll
    for (int j = 0; j < 2; ++j)
      bb[j] = *(const f16x8*)(Bs + (size_t)(ncol0 + j * 16) * 32 + lg * 8);
    #pragma unroll
    for (int m = 0; m < 8; ++m) {
      f16x8 ah = *(const f16x8*)(hb + (size_t)(m0 + m * 16 + lr) * 32 + lg * 8);
      acc[m][0] = __builtin_amdgcn_mfma_f32_16x16x32_f16(ah, bb[0], acc[m][0], 0, 0, 0);
      acc[m][1] = __builtin_amdgcn_mfma_f32_16x16x32_f16(ah, bb[1], acc[m][1], 0, 0, 0);
    }
  }
  // bias + store
  #pragma unroll
  for (int j = 0; j < 2; ++j) {
    int ocol = ncol0 + j * 16;
    float bv = bias[ocol];
    #pragma unroll
    for (int m = 0; m < 8; ++m) {
      int orow = m0 + m * 16 + lg * 4;
      #pragma unroll
      for (int r = 0; r < 4; ++r)
        out[(size_t)(orow + r) * OUT_F + ocol] = acc[m][j][r] + bv;
    }
  }
}

extern "C" void kernel_launch(void* const* d_in, const int* in_sizes, int n_in,
                              void* d_out, int out_size, void* d_ws, size_t ws_size,
                              hipStream_t stream) {
  const float* x       = (const float*)d_in[0];
  const float* scales  = (const float*)d_in[1];
  const float* bias    = (const float*)d_in[2];
  const float* lora_A  = (const float*)d_in[3];
  const float* lora_B  = (const float*)d_in[4];
  const int*   qweight = (const int*)d_in[5];
  const int*   qzeros  = (const int*)d_in[6];
  const int*   g_idx   = (const int*)d_in[7];
  float* out = (float*)d_out;

  if (ws_size < WS_NEED) return;

  char* ws = (char*)d_ws;
  unsigned short* xh  = (unsigned short*)(ws + OFF_XH);
  float* part         = (float*)(ws + OFF_PART);
  float* w            = (float*)(ws + OFF_W);
  float* bsum         = (float*)(ws + OFF_BSUM);
  float* inv          = (float*)(ws + OFF_INV);
  unsigned short* A_w = (unsigned short*)(ws + OFF_AW);
  unsigned short* Bs  = (unsigned short*)(ws + OFF_BS);
  float* hpart        = (float*)(ws + OFF_HPART);
  unsigned short* hb  = (unsigned short*)(ws + OFF_HB);

  k1_prep<<<dim3(2, 128), 256, 0, stream>>>(x, xh, part);
  k2_colred<<<16, 256, 0, stream>>>(part, w, bsum);
  k3a_inv<<<1, 64, 0, stream>>>(bsum, inv);
  k3b_fold<<<768, 256, 0, stream>>>(lora_A, lora_B, w, inv, A_w, Bs);
  k4_h<<<dim3(32, 8), 256, 0, stream>>>(xh, A_w, hpart);
  k5_hred<<<512, 256, 0, stream>>>(hpart, hb);
  k6_gemm<<<1024, 256, 0, stream>>>(xh, qweight, qzeros, scales, g_idx, bias, hb, Bs, out);
}

// Round 3
// 191.353 us; speedup vs baseline: 1.4408x; 1.0792x over previous
//
#include <hip/hip_runtime.h>
#include <stdint.h>

#define IN_F 4096
#define OUT_F 4096

typedef __attribute__((ext_vector_type(4))) float f32x4;
typedef _Float16 f16x8 __attribute__((ext_vector_type(8)));
typedef _Float16 f16x2 __attribute__((ext_vector_type(2)));
typedef unsigned short u16x8 __attribute__((ext_vector_type(8)));

__device__ __forceinline__ unsigned short f2h(float f) {
  _Float16 h = (_Float16)f;
  return __builtin_bit_cast(unsigned short, h);
}

// k-permutation within each 8-group: position p holds original column sigma(p),
// sigma = [0,4,1,5,2,6,3,7]  (matches packed-f16 dequant output order)
#define SIGMA_TAB 0x73625140u

// ---------------- workspace layout (bytes) ----------------
#define OFF_XH     ((size_t)0)            // f16 x (col-permuted) [4096][4096]
#define OFF_PART   ((size_t)33554432)     // f32 partials[128][4096]
#define OFF_W      ((size_t)35651584)     // f32 w[4096]
#define OFF_BSUM   ((size_t)35667968)     // f32 bsum[16]
#define OFF_AW     ((size_t)35668480)     // f16 A_w[16][4096] (col-permuted)
#define OFF_BS     ((size_t)35799552)     // f16 Bs[4096][32]
#define OFF_HPART  ((size_t)36061696)     // f32 hpart[8][4096][16]
#define OFF_HB     ((size_t)38158848)     // f16 hb[4096][32]
#define WS_NEED    ((size_t)38420992)

// K1: x -> f16 (columns permuted within 8-groups) + per-column |x| partials
__global__ __launch_bounds__(256) void k1_prep(const float* __restrict__ x,
                                               unsigned short* __restrict__ xh,
                                               float* __restrict__ part) {
  int t = threadIdx.x;
  int c8 = (blockIdx.x * 256 + t) * 8;
  int by = blockIdx.y;
  float a[8];
  #pragma unroll
  for (int i = 0; i < 8; ++i) a[i] = 0.f;
  for (int rr = 0; rr < 32; ++rr) {
    size_t off = (size_t)(by * 32 + rr) * IN_F + c8;
    f32x4 v0 = *(const f32x4*)(x + off);
    f32x4 v1 = *(const f32x4*)(x + off + 4);
    u16x8 o;
    o[0] = f2h(v0[0]); o[1] = f2h(v1[0]); o[2] = f2h(v0[1]); o[3] = f2h(v1[1]);
    o[4] = f2h(v0[2]); o[5] = f2h(v1[2]); o[6] = f2h(v0[3]); o[7] = f2h(v1[3]);
    *(u16x8*)(xh + off) = o;
    a[0] += fabsf(v0[0]); a[1] += fabsf(v0[1]); a[2] += fabsf(v0[2]); a[3] += fabsf(v0[3]);
    a[4] += fabsf(v1[0]); a[5] += fabsf(v1[1]); a[6] += fabsf(v1[2]); a[7] += fabsf(v1[3]);
  }
  f32x4 p0 = { a[0], a[1], a[2], a[3] };
  f32x4 p1 = { a[4], a[5], a[6], a[7] };
  *(f32x4*)(part + (size_t)by * IN_F + c8) = p0;
  *(f32x4*)(part + (size_t)by * IN_F + c8 + 4) = p1;
}

// K2: reduce stripes -> w[col]; per-block sums of w
__global__ __launch_bounds__(256) void k2_colred(const float* __restrict__ part,
                                                 float* __restrict__ w,
                                                 float* __restrict__ bsum) {
  int t = threadIdx.x;
  int col = blockIdx.x * 256 + t;
  float s = 0.f;
  for (int st = 0; st < 128; ++st) s += part[(size_t)st * IN_F + col];
  float wv = s * (1.0f / 4096.0f);
  w[col] = wv;
  __shared__ float red[256];
  red[t] = wv; __syncthreads();
  for (int k = 128; k > 0; k >>= 1) { if (t < k) red[t] += red[t + k]; __syncthreads(); }
  if (t == 0) bsum[blockIdx.x] = red[0];
}

// K3: A_w (col-permuted, f16);  Bs[o][r] = 2*(B0+B1) padded to 32 (f16)
// inv recomputed per block from bsum (deterministic, cheap)
__global__ __launch_bounds__(256) void k3_fold(const float* __restrict__ lora_A,
                                               const float* __restrict__ lora_B,
                                               const float* __restrict__ w,
                                               const float* __restrict__ bsum,
                                               unsigned short* __restrict__ A_w,
                                               unsigned short* __restrict__ Bs) {
  int b = blockIdx.x, t = threadIdx.x;
  float s = 0.f;
  #pragma unroll
  for (int i = 0; i < 16; ++i) s += bsum[i];
  float iv = 1.0f / (s * (1.0f / 4096.0f) + 1e-6f);
  if (b < 256) {
    int idx = b * 256 + t;                 // [16][4096]
    int r = idx >> 12;
    int pos = idx & 4095;
    int p = pos & 7;
    int orig = (pos & ~7) + (int)((SIGMA_TAB >> (p * 4)) & 7);
    float v = (lora_A[(size_t)r * IN_F + orig] + lora_A[(size_t)(16 + r) * IN_F + orig]) * w[orig] * iv;
    A_w[idx] = f2h(v);
  } else {
    int idx = (b - 256) * 256 + t;         // [4096][32]
    int o = idx >> 5, r = idx & 31;
    float v = 0.f;
    if (r < 16) v = 2.0f * (lora_B[o * 16 + r] + lora_B[OUT_F * 16 + o * 16 + r]);
    Bs[idx] = f2h(v);
  }
}

// K4: hpart[kc][m][r] = sum_{k in chunk} xh[m][k]*A_w[r][k]  (f16 MFMA, K-split)
__global__ __launch_bounds__(256) void k4_h(const unsigned short* __restrict__ xh,
                                            const unsigned short* __restrict__ A_w,
                                            float* __restrict__ hpart) {
  int mb = blockIdx.x, kc = blockIdx.y;
  int t = threadIdx.x, wid = t >> 6, l = t & 63;
  int m0 = mb * 128 + wid * 32;
  int lr = l & 15, lg = l >> 4;
  f32x4 z = { 0.f, 0.f, 0.f, 0.f };
  f32x4 acc0 = z, acc1 = z;
  for (int it = 0; it < 16; ++it) {
    int k = kc * 512 + it * 32 + lg * 8;
    f16x8 b  = *(const f16x8*)(A_w + (size_t)lr * IN_F + k);
    f16x8 a0 = *(const f16x8*)(xh + (size_t)(m0 + lr) * IN_F + k);
    f16x8 a1 = *(const f16x8*)(xh + (size_t)(m0 + 16 + lr) * IN_F + k);
    acc0 = __builtin_amdgcn_mfma_f32_16x16x32_f16(a0, b, acc0, 0, 0, 0);
    acc1 = __builtin_amdgcn_mfma_f32_16x16x32_f16(a1, b, acc1, 0, 0, 0);
  }
  float* hp = hpart + (size_t)kc * IN_F * 16;
  #pragma unroll
  for (int r = 0; r < 4; ++r) {
    hp[(size_t)(m0 + lg * 4 + r) * 16 + lr]      = acc0[r];
    hp[(size_t)(m0 + 16 + lg * 4 + r) * 16 + lr] = acc1[r];
  }
}

// K5: reduce K-chunks -> hb[m][32] f16 (cols 16..31 zero)
__global__ __launch_bounds__(256) void k5_hred(const float* __restrict__ hpart,
                                               unsigned short* __restrict__ hb) {
  int gid = blockIdx.x * 256 + threadIdx.x;
  int m = gid >> 5, r = gid & 31;
  float v = 0.f;
  if (r < 16)
    for (int kc = 0; kc < 8; ++kc) v += hpart[(size_t)kc * 65536 + m * 16 + r];
  hb[gid] = f2h(v);
}

// packed f16 dequant: int32 (8 nibbles) -> f16x8 fragment, k-order [0,4,1,5,2,6,3,7]
__device__ __forceinline__ f16x8 deq8(unsigned int q, f16x2 s2, f16x2 zz2) {
  unsigned int u0 = ( q         & 0x000F000Fu) | 0x64006400u;
  unsigned int u1 = ((q >> 4)   & 0x000F000Fu) | 0x64006400u;
  unsigned int u2 = ((q >> 8)   & 0x000F000Fu) | 0x64006400u;
  unsigned int u3 = ((q >> 12)  & 0x000F000Fu) | 0x64006400u;
  f16x2 w0 = (__builtin_bit_cast(f16x2, u0) - zz2) * s2;
  f16x2 w1 = (__builtin_bit_cast(f16x2, u1) - zz2) * s2;
  f16x2 w2 = (__builtin_bit_cast(f16x2, u2) - zz2) * s2;
  f16x2 w3 = (__builtin_bit_cast(f16x2, u3) - zz2) * s2;
  struct { f16x2 a, b, c, d; } r { w0, w1, w2, w3 };
  return __builtin_bit_cast(f16x8, r);
}

// K6: out = xh * W + bias + hb*Bs^T.  128x128 tile, 4 waves each owning 128x32.
// 2-phase double-buffered pipeline: stage t+1 (A glds + qweight regs) before
// computing tile t; one barrier per tile; setprio around MFMA clusters.
__global__ __launch_bounds__(256) void k6_gemm(const unsigned short* __restrict__ xh,
                                               const int* __restrict__ qweight,
                                               const int* __restrict__ qzeros,
                                               const float* __restrict__ scales,
                                               const float* __restrict__ bias,
                                               const unsigned short* __restrict__ hb,
                                               const unsigned short* __restrict__ Bs,
                                               float* __restrict__ out) {
  __shared__ __align__(16) unsigned short As[2][128 * 64];   // 2 x 16KB
  int t = threadIdx.x, w = t >> 6, l = t & 63;
  int lr = l & 15, lg = l >> 4;
  // XCD-aware swizzle: 1024 blocks, 8 XCDs -> each XCD owns a contiguous 128-chunk.
  // Within a chunk, 32 consecutive ids share mt -> one 1MB A-panel L2-resident/XCD.
  int b0 = blockIdx.x;
  int bid = (b0 & 7) * 128 + (b0 >> 3);
  int mt = bid >> 5, nt = bid & 31;
  int m0 = mt * 128, n0 = nt * 128;
  int ncol0 = n0 + w * 32 + lr;            // this lane's n for j=0 (j adds 16)

  f32x4 zz = { 0.f, 0.f, 0.f, 0.f };
  f32x4 acc[8][2];
  #pragma unroll
  for (int m = 0; m < 8; ++m) { acc[m][0] = zz; acc[m][1] = zz; }

  // ---- macros (static buf index; named reg sets per rule #20) ----
  #define STAGE_A(BUF, KT) do {                                                   \
    int k0_ = (KT) * 64;                                                          \
    _Pragma("unroll")                                                             \
    for (int it = 0; it < 4; ++it) {                                              \
      int idx = it * 256 + t;                                                     \
      int row = idx >> 3, c = idx & 7;                                            \
      int cp = c ^ (row & 7);                                                     \
      const unsigned short* gp = xh + (size_t)(m0 + row) * IN_F + k0_ + cp * 8;   \
      __builtin_amdgcn_global_load_lds((const __attribute__((address_space(1))) void*)gp, \
                                       (__attribute__((address_space(3))) void*)(&As[BUF][0] + idx * 8), \
                                       16, 0, 0);                                 \
    }                                                                             \
  } while (0)

  #define LOAD_QW(QW, KT) do {                                                    \
    int k0_ = (KT) * 64;                                                          \
    _Pragma("unroll")                                                             \
    for (int ks = 0; ks < 2; ++ks)                                                \
      _Pragma("unroll")                                                           \
      for (int j = 0; j < 2; ++j)                                                 \
        QW[j][ks] = (unsigned int)qweight[(size_t)((k0_ >> 3) + ks * 4 + lg) * OUT_F + ncol0 + j * 16]; \
  } while (0)

  #define LOAD_CONST(S2, ZP, GRP) do {                                            \
    _Pragma("unroll")                                                             \
    for (int j = 0; j < 2; ++j) {                                                 \
      int n = ncol0 + j * 16;                                                     \
      float s_ = scales[(size_t)(GRP) * OUT_F + n];                               \
      unsigned int zi = (unsigned int)qzeros[(GRP) * (OUT_F / 8) + (n >> 3)];     \
      unsigned int z = (zi >> ((n & 7) * 4)) & 0xFu;                              \
      unsigned int zzu = 0x64006400u + z * 0x00010001u;                           \
      ZP[j] = __builtin_bit_cast(f16x2, zzu);                                     \
      _Float16 sh = (_Float16)s_;                                                 \
      unsigned int sb = (unsigned int)__builtin_bit_cast(unsigned short, sh);     \
      unsigned int ssu = (sb << 16) | sb;                                         \
      S2[j] = __builtin_bit_cast(f16x2, ssu);                                     \
    }                                                                             \
  } while (0)

  #define COMPUTE(BUF, QW) do {                                                   \
    f16x8 bf[2][2];                                                               \
    _Pragma("unroll")                                                             \
    for (int ks = 0; ks < 2; ++ks)                                                \
      _Pragma("unroll")                                                           \
      for (int j = 0; j < 2; ++j)                                                 \
        bf[j][ks] = deq8(QW[j][ks], s2c[j], zpc[j]);                              \
    _Pragma("unroll")                                                             \
    for (int ks = 0; ks < 2; ++ks) {                                              \
      f16x8 a[8];                                                                 \
      _Pragma("unroll")                                                           \
      for (int m = 0; m < 8; ++m) {                                               \
        int row = m * 16 + lr;                                                    \
        int chunk = (ks * 4 + lg) ^ (lr & 7);                                     \
        a[m] = *(const f16x8*)(&As[BUF][0] + row * 64 + chunk * 8);               \
      }                                                                           \
      __builtin_amdgcn_s_setprio(1);                                              \
      _Pragma("unroll")                                                           \
      for (int m = 0; m < 8; ++m) {                                               \
        acc[m][0] = __builtin_amdgcn_mfma_f32_16x16x32_f16(a[m], bf[0][ks], acc[m][0], 0, 0, 0); \
        acc[m][1] = __builtin_amdgcn_mfma_f32_16x16x32_f16(a[m], bf[1][ks], acc[m][1], 0, 0, 0); \
      }                                                                           \
      __builtin_amdgcn_s_setprio(0);                                              \
    }                                                                             \
  } while (0)

  unsigned int qwA[2][2], qwB[2][2];
  f16x2 s2c[2], zpc[2];

  // prologue: stage tile 0, its qweights, and group-0 constants
  STAGE_A(0, 0);
  LOAD_QW(qwA, 0);
  LOAD_CONST(s2c, zpc, 0);
  __syncthreads();

  for (int kt = 0; kt < 64; kt += 2) {
    // phase E: prefetch kt+1 -> buf1/qwB, compute kt from buf0/qwA
    STAGE_A(1, kt + 1);                    // kt+1 <= 63 always
    LOAD_QW(qwB, kt + 1);
    COMPUTE(0, qwA);
    __syncthreads();
    // phase O: prefetch kt+2 -> buf0/qwA (+ next group consts), compute kt+1
    bool more = (kt + 2 < 64);
    f16x2 s2n[2], zpn[2];
    if (more) {
      STAGE_A(0, kt + 2);
      LOAD_QW(qwA, kt + 2);
      LOAD_CONST(s2n, zpn, (kt + 2) >> 1);
    }
    COMPUTE(1, qwB);
    __syncthreads();
    if (more) {
      s2c[0] = s2n[0]; s2c[1] = s2n[1];
      zpc[0] = zpn[0]; zpc[1] = zpn[1];
    }
  }
  #undef STAGE_A
  #undef LOAD_QW
  #undef LOAD_CONST
  #undef COMPUTE

  // epilogue: rank-16 LoRA as one K=32 f16 MFMA per fragment
  {
    f16x8 bb[2];
    #pragma unroll
    for (int j = 0; j < 2; ++j)
      bb[j] = *(const f16x8*)(Bs + (size_t)(ncol0 + j * 16) * 32 + lg * 8);
    #pragma unroll
    for (int m = 0; m < 8; ++m) {
      f16x8 ah = *(const f16x8*)(hb + (size_t)(m0 + m * 16 + lr) * 32 + lg * 8);
      acc[m][0] = __builtin_amdgcn_mfma_f32_16x16x32_f16(ah, bb[0], acc[m][0], 0, 0, 0);
      acc[m][1] = __builtin_amdgcn_mfma_f32_16x16x32_f16(ah, bb[1], acc[m][1], 0, 0, 0);
    }
  }
  // bias + store
  #pragma unroll
  for (int j = 0; j < 2; ++j) {
    int ocol = ncol0 + j * 16;
    float bv = bias[ocol];
    #pragma unroll
    for (int m = 0; m < 8; ++m) {
      int orow = m0 + m * 16 + lg * 4;
      #pragma unroll
      for (int r = 0; r < 4; ++r)
        out[(size_t)(orow + r) * OUT_F + ocol] = acc[m][j][r] + bv;
    }
  }
}

extern "C" void kernel_launch(void* const* d_in, const int* in_sizes, int n_in,
                              void* d_out, int out_size, void* d_ws, size_t ws_size,
                              hipStream_t stream) {
  const float* x       = (const float*)d_in[0];
  const float* scales  = (const float*)d_in[1];
  const float* bias    = (const float*)d_in[2];
  const float* lora_A  = (const float*)d_in[3];
  const float* lora_B  = (const float*)d_in[4];
  const int*   qweight = (const int*)d_in[5];
  const int*   qzeros  = (const int*)d_in[6];
  float* out = (float*)d_out;

  if (ws_size < WS_NEED) return;

  char* ws = (char*)d_ws;
  unsigned short* xh  = (unsigned short*)(ws + OFF_XH);
  float* part         = (float*)(ws + OFF_PART);
  float* w            = (float*)(ws + OFF_W);
  float* bsum         = (float*)(ws + OFF_BSUM);
  unsigned short* A_w = (unsigned short*)(ws + OFF_AW);
  unsigned short* Bs  = (unsigned short*)(ws + OFF_BS);
  float* hpart        = (float*)(ws + OFF_HPART);
  unsigned short* hb  = (unsigned short*)(ws + OFF_HB);

  k1_prep<<<dim3(2, 128), 256, 0, stream>>>(x, xh, part);
  k2_colred<<<16, 256, 0, stream>>>(part, w, bsum);
  k3_fold<<<768, 256, 0, stream>>>(lora_A, lora_B, w, bsum, A_w, Bs);
  k4_h<<<dim3(32, 8), 256, 0, stream>>>(xh, A_w, hpart);
  k5_hred<<<512, 256, 0, stream>>>(hpart, hb);
  k6_gemm<<<1024, 256, 0, stream>>>(xh, qweight, qzeros, scales, bias, hb, Bs, out);
}